// Round 9
// baseline (377.257 us; speedup 1.0000x reference)
//
#include <hip/hip_runtime.h>

#define NUSERS 50000
#define NITEMS 50000
#define NN (NUSERS + NITEMS)
#define KDIM 64
#define NLAYERS 3
#define FEAT 2048
#define NEDGES 2000000
#define BATCH 8192
#define SLOPE 0.2f

#define BSLOT 64            // fixed bucket capacity per node (max degree ~45 for Poisson(20); P(>64)~1e-15)
#define CNT_PAD 100352      // 98*1024, int4-zeroable cover of NN
#define XBLK 6250           // NN*KDIM/4 / 256
#define CBLK 98             // CNT_PAD/4/256
#define TBLK 128            // KDIM*FEAT/4/256
#define NNK (NN * KDIM)

typedef __attribute__((ext_vector_type(8))) short bf16x8;
typedef __attribute__((ext_vector_type(4))) float f32x4;

union U8 {
    bf16x8 v;
    uint4 u;
};

// round-to-nearest-even f32 -> bf16
__device__ __forceinline__ unsigned short f2bf(float f) {
    unsigned int u = __float_as_uint(f);
    unsigned int r = (u + 0x7fffu + ((u >> 16) & 1u)) >> 16;
    return (unsigned short)r;
}
__device__ __forceinline__ unsigned int pack2(float a, float b) {
    return (unsigned int)f2bf(a) | ((unsigned int)f2bf(b) << 16);
}
__device__ __forceinline__ float b2f(unsigned short h) {
    return __uint_as_float((unsigned int)h << 16);
}

// ---------------- setup: xh0 = bf16(concat(Gu,Gi)); cnt zero; pwh = bf16(proj_w) ----------------
__global__ __launch_bounds__(256) void setup_kernel(const float* __restrict__ Gu,
                                                    const float* __restrict__ Gi,
                                                    const float* __restrict__ pw,
                                                    unsigned short* __restrict__ xh,
                                                    int* __restrict__ cnt,
                                                    unsigned short* __restrict__ pwh) {
    int bx = blockIdx.x;
    if (bx < XBLK) {
        int i = bx * 256 + threadIdx.x;  // float4 index over NN*KDIM/4
        const int totalU = NUSERS * KDIM / 4;
        float4 v = (i < totalU) ? ((const float4*)Gu)[i] : ((const float4*)Gi)[i - totalU];
        ushort4 h;
        h.x = f2bf(v.x); h.y = f2bf(v.y); h.z = f2bf(v.z); h.w = f2bf(v.w);
        ((ushort4*)xh)[i] = h;
    } else if (bx < XBLK + CBLK) {
        int i = (bx - XBLK) * 256 + threadIdx.x;
        ((int4*)cnt)[i] = make_int4(0, 0, 0, 0);
    } else {
        int i = (bx - XBLK - CBLK) * 256 + threadIdx.x;  // float4 index over KDIM*FEAT/4
        float4 v = ((const float4*)pw)[i];
        ushort4 h;
        h.x = f2bf(v.x); h.y = f2bf(v.y); h.z = f2bf(v.z); h.w = f2bf(v.w);
        ((ushort4*)pwh)[i] = h;
    }
}

// ---------------- bucket build: one pass, atomic slot claim ----------------
__global__ __launch_bounds__(256) void fill_fixed_kernel(const int* __restrict__ ei,
                                                         const float* __restrict__ ew,
                                                         int* __restrict__ cnt,
                                                         int2* __restrict__ bucket) {
    int e = blockIdx.x * blockDim.x + threadIdx.x;
    if (e >= NEDGES) return;
    int src = ei[e];
    int dst = ei[NEDGES + e];
    int slot = atomicAdd(&cnt[dst], 1);
    if (slot < BSLOT)
        bucket[((long long)dst << 6) + slot] = make_int2(src, __float_as_int(ew[e]));
}

// ---------------- aggregate: aggh[n] = bf16( sum_edges w_e * xh[src_e] ) ----------------
// Edge-parallel: 64 lanes = 8 edge-groups (e8) x 8 dim-lanes (l8). One node at a time,
// 4 nodes per wave sequentially. 8 gathers in flight per round; shfl_xor butterfly reduce.
__global__ __launch_bounds__(256) void agg_kernel(const unsigned short* __restrict__ xh,
                                                  const int2* __restrict__ bucket,
                                                  const int* __restrict__ cnt,
                                                  unsigned short* __restrict__ aggh) {
    int t = threadIdx.x;
    int lane = t & 63, wid = t >> 6;
    int e8 = lane >> 3;  // edge group 0..7
    int l8 = lane & 7;   // dim group (8 bf16 dims)
    int nbase = (blockIdx.x * 4 + wid) * 4;
    const uint4* x4 = (const uint4*)xh;
#pragma unroll
    for (int ni = 0; ni < 4; ++ni) {
        int n = nbase + ni;
        if (n >= NN) break;
        int m = cnt[n];
        if (m > BSLOT) m = BSLOT;
        const int2* bk = bucket + ((long long)n << 6);
        float a[8];
#pragma unroll
        for (int q = 0; q < 8; ++q) a[q] = 0.f;
        for (int j = e8; j < m; j += 8) {
            int2 p = bk[j];
            uint4 u = x4[((long long)p.x << 3) + l8];
            float w = __int_as_float(p.y);
            a[0] += w * __uint_as_float(u.x << 16);
            a[1] += w * __uint_as_float(u.x & 0xFFFF0000u);
            a[2] += w * __uint_as_float(u.y << 16);
            a[3] += w * __uint_as_float(u.y & 0xFFFF0000u);
            a[4] += w * __uint_as_float(u.z << 16);
            a[5] += w * __uint_as_float(u.z & 0xFFFF0000u);
            a[6] += w * __uint_as_float(u.w << 16);
            a[7] += w * __uint_as_float(u.w & 0xFFFF0000u);
        }
        // butterfly reduce across e8 (lane bits 3,4,5)
#pragma unroll
        for (int q = 0; q < 8; ++q) {
            a[q] += __shfl_xor(a[q], 8);
            a[q] += __shfl_xor(a[q], 16);
            a[q] += __shfl_xor(a[q], 32);
        }
        if (e8 == 0) {
            uint4 o;
            o.x = pack2(a[0], a[1]); o.y = pack2(a[2], a[3]);
            o.z = pack2(a[4], a[5]); o.w = pack2(a[6], a[7]);
            *(uint4*)(aggh + (long long)n * KDIM + l8 * 8) = o;
        }
    }
}

// ---------------- NGCF layer via MFMA: xh_out = bf16(l2norm(leaky(S W1^T + b1 + P W2^T + b2))) ----------------
// Block 256 = 4 waves, 64-node tile. S,P,W1,W2 staged bf16 in LDS (rows padded to 72 shorts).
__global__ __launch_bounds__(256) void gemm_layer_kernel(const unsigned short* __restrict__ xh_in,
                                                         const unsigned short* __restrict__ aggh,
                                                         const float* __restrict__ W1,
                                                         const float* __restrict__ b1,
                                                         const float* __restrict__ W2,
                                                         const float* __restrict__ b2,
                                                         unsigned short* __restrict__ xhout,
                                                         int layer) {
    __shared__ unsigned short sS[64 * 72];
    __shared__ unsigned short sP[64 * 72];
    __shared__ unsigned short sW1[64 * 72];
    __shared__ unsigned short sW2[64 * 72];
    int t = threadIdx.x;
    const float* W1g = W1 + (long long)layer * KDIM * KDIM;
    const float* W2g = W2 + (long long)layer * KDIM * KDIM;
    // stage weights bf16 row-major [n][k] (B^T layout)
    for (int idx = t; idx < KDIM * KDIM; idx += 256) {
        int j = idx >> 6, k = idx & 63;
        sW1[j * 72 + k] = f2bf(W1g[idx]);
        sW2[j * 72 + k] = f2bf(W2g[idx]);
    }
    // stage S = x+agg, P = x*agg (bf16 inputs, bf16 out)
    int n0 = blockIdx.x * 64;
    {
        int r = t >> 2, q = t & 3;
        int node = n0 + r;
        unsigned short* dS = &sS[r * 72 + q * 16];
        unsigned short* dP = &sP[r * 72 + q * 16];
        if (node < NN) {
            const unsigned short* xb = xh_in + (long long)node * KDIM + q * 16;
            const unsigned short* ab = aggh + (long long)node * KDIM + q * 16;
            uint4 hx = *(const uint4*)xb;
            uint4 hx2 = *(const uint4*)(xb + 8);
            uint4 ha = *(const uint4*)ab;
            uint4 ha2 = *(const uint4*)(ab + 8);
            uint4 swv, pwv, swv2, pwv2;
#define PROC(XW, AW, SW, PW)                                                        \
            {                                                                       \
                float xx0 = __uint_as_float((XW) << 16);                            \
                float xx1 = __uint_as_float((XW) & 0xFFFF0000u);                    \
                float aa0 = __uint_as_float((AW) << 16);                            \
                float aa1 = __uint_as_float((AW) & 0xFFFF0000u);                    \
                SW = pack2(xx0 + aa0, xx1 + aa1);                                   \
                PW = pack2(xx0 * aa0, xx1 * aa1);                                   \
            }
            PROC(hx.x, ha.x, swv.x, pwv.x)
            PROC(hx.y, ha.y, swv.y, pwv.y)
            PROC(hx.z, ha.z, swv.z, pwv.z)
            PROC(hx.w, ha.w, swv.w, pwv.w)
            PROC(hx2.x, ha2.x, swv2.x, pwv2.x)
            PROC(hx2.y, ha2.y, swv2.y, pwv2.y)
            PROC(hx2.z, ha2.z, swv2.z, pwv2.z)
            PROC(hx2.w, ha2.w, swv2.w, pwv2.w)
#undef PROC
            *(uint4*)dS = swv;
            *(uint4*)(dS + 8) = swv2;
            *(uint4*)dP = pwv;
            *(uint4*)(dP + 8) = pwv2;
        } else {
            uint4 z = make_uint4(0, 0, 0, 0);
            *(uint4*)dS = z; *(uint4*)(dS + 8) = z;
            *(uint4*)dP = z; *(uint4*)(dP + 8) = z;
        }
    }
    __syncthreads();

    int l = t & 63, w = t >> 6, m16 = l & 15, g4 = l >> 4;
    f32x4 acc[4];
#pragma unroll
    for (int c = 0; c < 4; ++c) {
        float bb = b1[layer * KDIM + c * 16 + m16] + b2[layer * KDIM + c * 16 + m16];
        acc[c] = (f32x4){bb, bb, bb, bb};
    }
    const int abase = (w * 16 + m16) * 72;
#pragma unroll
    for (int kh = 0; kh < 2; ++kh) {
        int ko = kh * 32 + g4 * 8;
        bf16x8 aS = *(const bf16x8*)&sS[abase + ko];
        bf16x8 aP = *(const bf16x8*)&sP[abase + ko];
#pragma unroll
        for (int c = 0; c < 4; ++c) {
            bf16x8 bw1 = *(const bf16x8*)&sW1[(c * 16 + m16) * 72 + ko];
            acc[c] = __builtin_amdgcn_mfma_f32_16x16x32_bf16(aS, bw1, acc[c], 0, 0, 0);
            bf16x8 bw2 = *(const bf16x8*)&sW2[(c * 16 + m16) * 72 + ko];
            acc[c] = __builtin_amdgcn_mfma_f32_16x16x32_bf16(aP, bw2, acc[c], 0, 0, 0);
        }
    }

    // epilogue: leaky, per-row l2norm (rows = g4*4+reg; cols = c*16+m16), store bf16
    float sq[4] = {0.f, 0.f, 0.f, 0.f};
#pragma unroll
    for (int c = 0; c < 4; ++c) {
#pragma unroll
        for (int reg = 0; reg < 4; ++reg) {
            float h = acc[c][reg];
            h = h > 0.f ? h : SLOPE * h;
            acc[c][reg] = h;
            sq[reg] += h * h;
        }
    }
#pragma unroll
    for (int reg = 0; reg < 4; ++reg) {
#pragma unroll
        for (int off = 1; off < 16; off <<= 1) sq[reg] += __shfl_xor(sq[reg], off);
        sq[reg] = 1.0f / fmaxf(sqrtf(sq[reg]), 1e-12f);
    }
#pragma unroll
    for (int reg = 0; reg < 4; ++reg) {
        int node = n0 + w * 16 + g4 * 4 + reg;
        if (node < NN) {
#pragma unroll
            for (int c = 0; c < 4; ++c)
                xhout[(long long)node * KDIM + c * 16 + m16] = f2bf(acc[c][reg] * sq[reg]);
        }
    }
}

// ---------------- projection via MFMA, split-K over 8 waves ----------------
__global__ __launch_bounds__(512) void proj_kernel(const float* __restrict__ F,
                                                   const unsigned short* __restrict__ pwh,
                                                   const float* __restrict__ pb,
                                                   const int* __restrict__ items,
                                                   float* __restrict__ projB) {
    __shared__ float lds[8][64][16];
    int t = threadIdx.x;
    int l = t & 63, w = t >> 6, m16 = l & 15, g4 = l >> 4;
    int i0 = blockIdx.x * 16;
    int item = items[i0 + m16];
    const float* frow = F + (long long)item * FEAT + g4 * 8;
    f32x4 acc[4];
#pragma unroll
    for (int c = 0; c < 4; ++c) acc[c] = (f32x4){0.f, 0.f, 0.f, 0.f};
    float4 fa[8], fb[8];
#pragma unroll
    for (int u = 0; u < 8; ++u) {
        const float* p = frow + (w * 8 + u) * 32;
        fa[u] = *(const float4*)p;
        fb[u] = *(const float4*)(p + 4);
    }
#pragma unroll
    for (int u = 0; u < 8; ++u) {
        U8 af;
        af.u = make_uint4(pack2(fa[u].x, fa[u].y), pack2(fa[u].z, fa[u].w),
                          pack2(fb[u].x, fb[u].y), pack2(fb[u].z, fb[u].w));
#pragma unroll
        for (int c = 0; c < 4; ++c) {
            bf16x8 bw = *(const bf16x8*)(pwh + (long long)(c * 16 + m16) * FEAT +
                                         (w * 8 + u) * 32 + g4 * 8);
            acc[c] = __builtin_amdgcn_mfma_f32_16x16x32_bf16(af.v, bw, acc[c], 0, 0, 0);
        }
    }
#pragma unroll
    for (int c = 0; c < 4; ++c)
#pragma unroll
        for (int reg = 0; reg < 4; ++reg) lds[w][l][c * 4 + reg] = acc[c][reg];
    __syncthreads();
    for (int e = t; e < 1024; e += 512) {
        int ll = e >> 4, v = e & 15;
        float s = lds[0][ll][v];
#pragma unroll
        for (int ww = 1; ww < 8; ++ww) s += lds[ww][ll][v];
        lds[0][ll][v] = s;
    }
    __syncthreads();
    if (w == 0) {
        float av[4][4];
        float sq[4] = {0.f, 0.f, 0.f, 0.f};
#pragma unroll
        for (int c = 0; c < 4; ++c) {
            float bb = pb[c * 16 + m16];
#pragma unroll
            for (int reg = 0; reg < 4; ++reg) {
                float h = lds[0][l][c * 4 + reg] + bb;
                av[c][reg] = h;
                sq[reg] += h * h;
            }
        }
#pragma unroll
        for (int reg = 0; reg < 4; ++reg) {
#pragma unroll
            for (int off = 1; off < 16; off <<= 1) sq[reg] += __shfl_xor(sq[reg], off);
            sq[reg] = 1.0f / fmaxf(sqrtf(sq[reg]), 1e-12f);
        }
#pragma unroll
        for (int reg = 0; reg < 4; ++reg) {
            int b = i0 + g4 * 4 + reg;
#pragma unroll
            for (int c = 0; c < 4; ++c)
                projB[(long long)b * KDIM + c * 16 + m16] = av[c][reg] * sq[reg];
        }
    }
}

// ---------------- final: mean over xh0..xh3 rows + dots ----------------
__global__ __launch_bounds__(256) void final_kernel(const unsigned short* __restrict__ xh0,
                                                    const unsigned short* __restrict__ xh1,
                                                    const unsigned short* __restrict__ xh2,
                                                    const unsigned short* __restrict__ xh3,
                                                    const float* __restrict__ Tu,
                                                    const float* __restrict__ projB,
                                                    const int* __restrict__ users,
                                                    const int* __restrict__ items,
                                                    float* __restrict__ out) {
    int lane = threadIdx.x & 63;
    int wid = threadIdx.x >> 6;
    int b = blockIdx.x * 4 + wid;
    if (b >= BATCH) return;
    int u = users[b];
    int it = NUSERS + items[b];
    long long uo = (long long)u * KDIM + lane;
    long long io = (long long)it * KDIM + lane;
    float gu = b2f(xh0[uo]) + b2f(xh1[uo]) + b2f(xh2[uo]) + b2f(xh3[uo]);
    float gi = b2f(xh0[io]) + b2f(xh1[io]) + b2f(xh2[io]) + b2f(xh3[io]);
    float tu = Tu[(long long)u * KDIM + lane];
    float pi = projB[(long long)b * KDIM + lane];
    float v = gu * gi * (1.0f / 16.0f) + tu * pi;
#pragma unroll
    for (int off = 32; off > 0; off >>= 1) v += __shfl_xor(v, off);
    if (lane == 0) out[b] = v;
}

extern "C" void kernel_launch(void* const* d_in, const int* in_sizes, int n_in,
                              void* d_out, int out_size, void* d_ws, size_t ws_size,
                              hipStream_t stream) {
    const float* Gu = (const float*)d_in[0];
    const float* Gi = (const float*)d_in[1];
    const float* Tu = (const float*)d_in[2];
    const float* F = (const float*)d_in[3];
    const float* pw = (const float*)d_in[4];
    const float* pb = (const float*)d_in[5];
    const float* W1 = (const float*)d_in[6];
    const float* b1 = (const float*)d_in[7];
    const float* W2 = (const float*)d_in[8];
    const float* b2 = (const float*)d_in[9];
    const float* ew = (const float*)d_in[10];
    const int* ei = (const int*)d_in[11];
    const int* users = (const int*)d_in[12];
    const int* items = (const int*)d_in[13];
    float* out = (float*)d_out;

    float* projB = (float*)d_ws;                            // BATCH*KDIM f32
    int2* bucket = (int2*)(projB + (size_t)BATCH * KDIM);   // NN*BSLOT int2
    int* cnt = (int*)(bucket + (size_t)NN * BSLOT);         // CNT_PAD int
    unsigned short* aggh = (unsigned short*)(cnt + CNT_PAD);  // NNK bf16
    unsigned short* pwh = aggh + (size_t)NNK;                 // KDIM*FEAT bf16
    unsigned short* xh0 = pwh + (size_t)KDIM * FEAT;          // NNK bf16 x4
    unsigned short* xh1 = xh0 + (size_t)NNK;
    unsigned short* xh2 = xh1 + (size_t)NNK;
    unsigned short* xh3 = xh2 + (size_t)NNK;

    setup_kernel<<<XBLK + CBLK + TBLK, 256, 0, stream>>>(Gu, Gi, pw, xh0, cnt, pwh);
    fill_fixed_kernel<<<(NEDGES + 255) / 256, 256, 0, stream>>>(ei, ew, cnt, bucket);

    unsigned short* xs[4] = {xh0, xh1, xh2, xh3};
    for (int ll = 0; ll < NLAYERS; ++ll) {
        agg_kernel<<<(NN + 15) / 16, 256, 0, stream>>>(xs[ll], bucket, cnt, aggh);
        gemm_layer_kernel<<<(NN + 63) / 64, 256, 0, stream>>>(xs[ll], aggh, W1, b1, W2, b2,
                                                              xs[ll + 1], ll);
    }

    proj_kernel<<<BATCH / 16, 512, 0, stream>>>(F, pwh, pb, items, projB);
    final_kernel<<<BATCH / 4, 256, 0, stream>>>(xh0, xh1, xh2, xh3, Tu, projB, users, items, out);
}

// Round 10
// 338.424 us; speedup vs baseline: 1.1147x; 1.1147x over previous
//
#include <hip/hip_runtime.h>

#define NUSERS 50000
#define NITEMS 50000
#define NN (NUSERS + NITEMS)
#define KDIM 64
#define NLAYERS 3
#define FEAT 2048
#define NEDGES 2000000
#define BATCH 8192
#define SLOPE 0.2f

#define BSLOT 64            // fixed bucket capacity per node (max degree ~45 for Poisson(20))
#define CNT_PAD 100352      // 98*1024, int4-zeroable cover of NN
#define XBLK 6250           // NN*KDIM/4 / 256
#define CBLK 98             // CNT_PAD/4/256
#define TBLK 128            // KDIM*FEAT/4/256
#define NNK (NN * KDIM)
#define PROJ_BLOCKS (BATCH / 16)          // 512
#define AGG_BLOCKS ((NN + 63) / 64)       // 1563 (64 nodes per 8-wave block)

typedef __attribute__((ext_vector_type(8))) short bf16x8;
typedef __attribute__((ext_vector_type(4))) float f32x4;

union U8 {
    bf16x8 v;
    uint4 u;
};

// round-to-nearest-even f32 -> bf16
__device__ __forceinline__ unsigned short f2bf(float f) {
    unsigned int u = __float_as_uint(f);
    unsigned int r = (u + 0x7fffu + ((u >> 16) & 1u)) >> 16;
    return (unsigned short)r;
}
__device__ __forceinline__ unsigned int pack2(float a, float b) {
    return (unsigned int)f2bf(a) | ((unsigned int)f2bf(b) << 16);
}
__device__ __forceinline__ float b2f(unsigned short h) {
    return __uint_as_float((unsigned int)h << 16);
}

// ---------------- setup: xh0 = bf16(concat(Gu,Gi)); cnt zero; pwh = bf16(proj_w) ----------------
__global__ __launch_bounds__(256) void setup_kernel(const float* __restrict__ Gu,
                                                    const float* __restrict__ Gi,
                                                    const float* __restrict__ pw,
                                                    unsigned short* __restrict__ xh,
                                                    int* __restrict__ cnt,
                                                    unsigned short* __restrict__ pwh) {
    int bx = blockIdx.x;
    if (bx < XBLK) {
        int i = bx * 256 + threadIdx.x;  // float4 index over NN*KDIM/4
        const int totalU = NUSERS * KDIM / 4;
        float4 v = (i < totalU) ? ((const float4*)Gu)[i] : ((const float4*)Gi)[i - totalU];
        ushort4 h;
        h.x = f2bf(v.x); h.y = f2bf(v.y); h.z = f2bf(v.z); h.w = f2bf(v.w);
        ((ushort4*)xh)[i] = h;
    } else if (bx < XBLK + CBLK) {
        int i = (bx - XBLK) * 256 + threadIdx.x;
        ((int4*)cnt)[i] = make_int4(0, 0, 0, 0);
    } else {
        int i = (bx - XBLK - CBLK) * 256 + threadIdx.x;  // float4 index over KDIM*FEAT/4
        float4 v = ((const float4*)pw)[i];
        ushort4 h;
        h.x = f2bf(v.x); h.y = f2bf(v.y); h.z = f2bf(v.z); h.w = f2bf(v.w);
        ((ushort4*)pwh)[i] = h;
    }
}

// ---------------- bucket build: one pass, atomic slot claim ----------------
__global__ __launch_bounds__(256) void fill_fixed_kernel(const int* __restrict__ ei,
                                                         const float* __restrict__ ew,
                                                         int* __restrict__ cnt,
                                                         int2* __restrict__ bucket) {
    int e = blockIdx.x * blockDim.x + threadIdx.x;
    if (e >= NEDGES) return;
    int src = ei[e];
    int dst = ei[NEDGES + e];
    int slot = atomicAdd(&cnt[dst], 1);
    if (slot < BSLOT)
        bucket[((long long)dst << 6) + slot] = make_int2(src, __float_as_int(ew[e]));
}

// ---------------- agg inner body (round-8 proven form): 8 lanes/node, unroll x4 ----------------
__device__ __forceinline__ void agg_node(const unsigned short* __restrict__ xh,
                                         const int2* __restrict__ bucket,
                                         const int* __restrict__ cnt,
                                         unsigned short* __restrict__ aggh, int n, int l8) {
    int m = cnt[n];
    if (m > BSLOT) m = BSLOT;
    const int2* bk = bucket + ((long long)n << 6);
    const uint4* x4 = (const uint4*)xh;  // row stride 8 uint4
    float a0[8], a1[8], a2[8], a3[8];
#pragma unroll
    for (int q = 0; q < 8; ++q) { a0[q] = 0.f; a1[q] = 0.f; a2[q] = 0.f; a3[q] = 0.f; }
    int j = 0;
    for (; j + 4 <= m; j += 4) {
        int2 p0 = bk[j], p1 = bk[j + 1], p2 = bk[j + 2], p3 = bk[j + 3];
        uint4 u0 = x4[((long long)p0.x << 3) + l8];
        uint4 u1 = x4[((long long)p1.x << 3) + l8];
        uint4 u2 = x4[((long long)p2.x << 3) + l8];
        uint4 u3 = x4[((long long)p3.x << 3) + l8];
        float w0 = __int_as_float(p0.y), w1 = __int_as_float(p1.y);
        float w2 = __int_as_float(p2.y), w3 = __int_as_float(p3.y);
        a0[0] += w0 * __uint_as_float(u0.x << 16); a0[1] += w0 * __uint_as_float(u0.x & 0xFFFF0000u);
        a0[2] += w0 * __uint_as_float(u0.y << 16); a0[3] += w0 * __uint_as_float(u0.y & 0xFFFF0000u);
        a0[4] += w0 * __uint_as_float(u0.z << 16); a0[5] += w0 * __uint_as_float(u0.z & 0xFFFF0000u);
        a0[6] += w0 * __uint_as_float(u0.w << 16); a0[7] += w0 * __uint_as_float(u0.w & 0xFFFF0000u);
        a1[0] += w1 * __uint_as_float(u1.x << 16); a1[1] += w1 * __uint_as_float(u1.x & 0xFFFF0000u);
        a1[2] += w1 * __uint_as_float(u1.y << 16); a1[3] += w1 * __uint_as_float(u1.y & 0xFFFF0000u);
        a1[4] += w1 * __uint_as_float(u1.z << 16); a1[5] += w1 * __uint_as_float(u1.z & 0xFFFF0000u);
        a1[6] += w1 * __uint_as_float(u1.w << 16); a1[7] += w1 * __uint_as_float(u1.w & 0xFFFF0000u);
        a2[0] += w2 * __uint_as_float(u2.x << 16); a2[1] += w2 * __uint_as_float(u2.x & 0xFFFF0000u);
        a2[2] += w2 * __uint_as_float(u2.y << 16); a2[3] += w2 * __uint_as_float(u2.y & 0xFFFF0000u);
        a2[4] += w2 * __uint_as_float(u2.z << 16); a2[5] += w2 * __uint_as_float(u2.z & 0xFFFF0000u);
        a2[6] += w2 * __uint_as_float(u2.w << 16); a2[7] += w2 * __uint_as_float(u2.w & 0xFFFF0000u);
        a3[0] += w3 * __uint_as_float(u3.x << 16); a3[1] += w3 * __uint_as_float(u3.x & 0xFFFF0000u);
        a3[2] += w3 * __uint_as_float(u3.y << 16); a3[3] += w3 * __uint_as_float(u3.y & 0xFFFF0000u);
        a3[4] += w3 * __uint_as_float(u3.z << 16); a3[5] += w3 * __uint_as_float(u3.z & 0xFFFF0000u);
        a3[6] += w3 * __uint_as_float(u3.w << 16); a3[7] += w3 * __uint_as_float(u3.w & 0xFFFF0000u);
    }
    for (; j < m; ++j) {
        int2 p0 = bk[j];
        uint4 u0 = x4[((long long)p0.x << 3) + l8];
        float w0 = __int_as_float(p0.y);
        a0[0] += w0 * __uint_as_float(u0.x << 16); a0[1] += w0 * __uint_as_float(u0.x & 0xFFFF0000u);
        a0[2] += w0 * __uint_as_float(u0.y << 16); a0[3] += w0 * __uint_as_float(u0.y & 0xFFFF0000u);
        a0[4] += w0 * __uint_as_float(u0.z << 16); a0[5] += w0 * __uint_as_float(u0.z & 0xFFFF0000u);
        a0[6] += w0 * __uint_as_float(u0.w << 16); a0[7] += w0 * __uint_as_float(u0.w & 0xFFFF0000u);
    }
#pragma unroll
    for (int q = 0; q < 8; ++q) a0[q] = (a0[q] + a1[q]) + (a2[q] + a3[q]);
    uint4 o;
    o.x = pack2(a0[0], a0[1]); o.y = pack2(a0[2], a0[3]);
    o.z = pack2(a0[4], a0[5]); o.w = pack2(a0[6], a0[7]);
    *(uint4*)(aggh + (long long)n * KDIM + l8 * 8) = o;
}

// ---------------- standalone aggregate (layers 1,2): 256 thr, 8 nodes/wave ----------------
__global__ __launch_bounds__(256) void agg_kernel(const unsigned short* __restrict__ xh,
                                                  const int2* __restrict__ bucket,
                                                  const int* __restrict__ cnt,
                                                  unsigned short* __restrict__ aggh) {
    int t = threadIdx.x;
    int lane = t & 63, wid = t >> 6;
    int g = lane >> 3, l8 = lane & 7;
    int n = (blockIdx.x * 4 + wid) * 8 + g;
    if (n >= NN) return;
    agg_node(xh, bucket, cnt, aggh, n, l8);
}

// ---------------- merged: proj (blocks [0,512)) + agg layer 0 (rest), 512 thr ----------------
__global__ __launch_bounds__(512) void proj_agg0_kernel(const float* __restrict__ F,
                                                        const unsigned short* __restrict__ pwh,
                                                        const float* __restrict__ pb,
                                                        const int* __restrict__ items,
                                                        float* __restrict__ projB,
                                                        const unsigned short* __restrict__ xh,
                                                        const int2* __restrict__ bucket,
                                                        const int* __restrict__ cnt,
                                                        unsigned short* __restrict__ aggh) {
    __shared__ float lds[8][64][16];
    int t = threadIdx.x;
    int l = t & 63, w = t >> 6, m16 = l & 15, g4 = l >> 4;
    if (blockIdx.x >= PROJ_BLOCKS) {
        // ---- agg layer 0: 8 waves x 8 nodes ----
        int n = (blockIdx.x - PROJ_BLOCKS) * 64 + w * 8 + (l >> 3);
        if (n < NN) agg_node(xh, bucket, cnt, aggh, n, l & 7);
        return;
    }
    // ---- projection via MFMA, split-K over 8 waves ----
    int i0 = blockIdx.x * 16;
    int item = items[i0 + m16];
    const float* frow = F + (long long)item * FEAT + g4 * 8;
    f32x4 acc[4];
#pragma unroll
    for (int c = 0; c < 4; ++c) acc[c] = (f32x4){0.f, 0.f, 0.f, 0.f};
    float4 fa[8], fb[8];
#pragma unroll
    for (int u = 0; u < 8; ++u) {
        const float* p = frow + (w * 8 + u) * 32;
        fa[u] = *(const float4*)p;
        fb[u] = *(const float4*)(p + 4);
    }
#pragma unroll
    for (int u = 0; u < 8; ++u) {
        U8 af;
        af.u = make_uint4(pack2(fa[u].x, fa[u].y), pack2(fa[u].z, fa[u].w),
                          pack2(fb[u].x, fb[u].y), pack2(fb[u].z, fb[u].w));
#pragma unroll
        for (int c = 0; c < 4; ++c) {
            bf16x8 bw = *(const bf16x8*)(pwh + (long long)(c * 16 + m16) * FEAT +
                                         (w * 8 + u) * 32 + g4 * 8);
            acc[c] = __builtin_amdgcn_mfma_f32_16x16x32_bf16(af.v, bw, acc[c], 0, 0, 0);
        }
    }
#pragma unroll
    for (int c = 0; c < 4; ++c)
#pragma unroll
        for (int reg = 0; reg < 4; ++reg) lds[w][l][c * 4 + reg] = acc[c][reg];
    __syncthreads();
    for (int e = t; e < 1024; e += 512) {
        int ll = e >> 4, v = e & 15;
        float s = lds[0][ll][v];
#pragma unroll
        for (int ww = 1; ww < 8; ++ww) s += lds[ww][ll][v];
        lds[0][ll][v] = s;
    }
    __syncthreads();
    if (w == 0) {
        float av[4][4];
        float sq[4] = {0.f, 0.f, 0.f, 0.f};
#pragma unroll
        for (int c = 0; c < 4; ++c) {
            float bb = pb[c * 16 + m16];
#pragma unroll
            for (int reg = 0; reg < 4; ++reg) {
                float h = lds[0][l][c * 4 + reg] + bb;
                av[c][reg] = h;
                sq[reg] += h * h;
            }
        }
#pragma unroll
        for (int reg = 0; reg < 4; ++reg) {
#pragma unroll
            for (int off = 1; off < 16; off <<= 1) sq[reg] += __shfl_xor(sq[reg], off);
            sq[reg] = 1.0f / fmaxf(sqrtf(sq[reg]), 1e-12f);
        }
#pragma unroll
        for (int reg = 0; reg < 4; ++reg) {
            int b = i0 + g4 * 4 + reg;
#pragma unroll
            for (int c = 0; c < 4; ++c)
                projB[(long long)b * KDIM + c * 16 + m16] = av[c][reg] * sq[reg];
        }
    }
}

// ---------------- NGCF layer via MFMA: xh_out = bf16(l2norm(leaky(S W1^T + b1 + P W2^T + b2))) ----------------
__global__ __launch_bounds__(256) void gemm_layer_kernel(const unsigned short* __restrict__ xh_in,
                                                         const unsigned short* __restrict__ aggh,
                                                         const float* __restrict__ W1,
                                                         const float* __restrict__ b1,
                                                         const float* __restrict__ W2,
                                                         const float* __restrict__ b2,
                                                         unsigned short* __restrict__ xhout,
                                                         int layer) {
    __shared__ unsigned short sS[64 * 72];
    __shared__ unsigned short sP[64 * 72];
    __shared__ unsigned short sW1[64 * 72];
    __shared__ unsigned short sW2[64 * 72];
    int t = threadIdx.x;
    const float* W1g = W1 + (long long)layer * KDIM * KDIM;
    const float* W2g = W2 + (long long)layer * KDIM * KDIM;
    for (int idx = t; idx < KDIM * KDIM; idx += 256) {
        int j = idx >> 6, k = idx & 63;
        sW1[j * 72 + k] = f2bf(W1g[idx]);
        sW2[j * 72 + k] = f2bf(W2g[idx]);
    }
    int n0 = blockIdx.x * 64;
    {
        int r = t >> 2, q = t & 3;
        int node = n0 + r;
        unsigned short* dS = &sS[r * 72 + q * 16];
        unsigned short* dP = &sP[r * 72 + q * 16];
        if (node < NN) {
            const unsigned short* xb = xh_in + (long long)node * KDIM + q * 16;
            const unsigned short* ab = aggh + (long long)node * KDIM + q * 16;
            uint4 hx = *(const uint4*)xb;
            uint4 hx2 = *(const uint4*)(xb + 8);
            uint4 ha = *(const uint4*)ab;
            uint4 ha2 = *(const uint4*)(ab + 8);
            uint4 swv, pwv, swv2, pwv2;
#define PROC(XW, AW, SW, PW)                                                        \
            {                                                                       \
                float xx0 = __uint_as_float((XW) << 16);                            \
                float xx1 = __uint_as_float((XW) & 0xFFFF0000u);                    \
                float aa0 = __uint_as_float((AW) << 16);                            \
                float aa1 = __uint_as_float((AW) & 0xFFFF0000u);                    \
                SW = pack2(xx0 + aa0, xx1 + aa1);                                   \
                PW = pack2(xx0 * aa0, xx1 * aa1);                                   \
            }
            PROC(hx.x, ha.x, swv.x, pwv.x)
            PROC(hx.y, ha.y, swv.y, pwv.y)
            PROC(hx.z, ha.z, swv.z, pwv.z)
            PROC(hx.w, ha.w, swv.w, pwv.w)
            PROC(hx2.x, ha2.x, swv2.x, pwv2.x)
            PROC(hx2.y, ha2.y, swv2.y, pwv2.y)
            PROC(hx2.z, ha2.z, swv2.z, pwv2.z)
            PROC(hx2.w, ha2.w, swv2.w, pwv2.w)
#undef PROC
            *(uint4*)dS = swv;
            *(uint4*)(dS + 8) = swv2;
            *(uint4*)dP = pwv;
            *(uint4*)(dP + 8) = pwv2;
        } else {
            uint4 z = make_uint4(0, 0, 0, 0);
            *(uint4*)dS = z; *(uint4*)(dS + 8) = z;
            *(uint4*)dP = z; *(uint4*)(dP + 8) = z;
        }
    }
    __syncthreads();

    int l = t & 63, w = t >> 6, m16 = l & 15, g4 = l >> 4;
    f32x4 acc[4];
#pragma unroll
    for (int c = 0; c < 4; ++c) {
        float bb = b1[layer * KDIM + c * 16 + m16] + b2[layer * KDIM + c * 16 + m16];
        acc[c] = (f32x4){bb, bb, bb, bb};
    }
    const int abase = (w * 16 + m16) * 72;
#pragma unroll
    for (int kh = 0; kh < 2; ++kh) {
        int ko = kh * 32 + g4 * 8;
        bf16x8 aS = *(const bf16x8*)&sS[abase + ko];
        bf16x8 aP = *(const bf16x8*)&sP[abase + ko];
#pragma unroll
        for (int c = 0; c < 4; ++c) {
            bf16x8 bw1 = *(const bf16x8*)&sW1[(c * 16 + m16) * 72 + ko];
            acc[c] = __builtin_amdgcn_mfma_f32_16x16x32_bf16(aS, bw1, acc[c], 0, 0, 0);
            bf16x8 bw2 = *(const bf16x8*)&sW2[(c * 16 + m16) * 72 + ko];
            acc[c] = __builtin_amdgcn_mfma_f32_16x16x32_bf16(aP, bw2, acc[c], 0, 0, 0);
        }
    }

    float sq[4] = {0.f, 0.f, 0.f, 0.f};
#pragma unroll
    for (int c = 0; c < 4; ++c) {
#pragma unroll
        for (int reg = 0; reg < 4; ++reg) {
            float h = acc[c][reg];
            h = h > 0.f ? h : SLOPE * h;
            acc[c][reg] = h;
            sq[reg] += h * h;
        }
    }
#pragma unroll
    for (int reg = 0; reg < 4; ++reg) {
#pragma unroll
        for (int off = 1; off < 16; off <<= 1) sq[reg] += __shfl_xor(sq[reg], off);
        sq[reg] = 1.0f / fmaxf(sqrtf(sq[reg]), 1e-12f);
    }
#pragma unroll
    for (int reg = 0; reg < 4; ++reg) {
        int node = n0 + w * 16 + g4 * 4 + reg;
        if (node < NN) {
#pragma unroll
            for (int c = 0; c < 4; ++c)
                xhout[(long long)node * KDIM + c * 16 + m16] = f2bf(acc[c][reg] * sq[reg]);
        }
    }
}

// ---------------- final: mean over xh0..xh3 rows + dots ----------------
__global__ __launch_bounds__(256) void final_kernel(const unsigned short* __restrict__ xh0,
                                                    const unsigned short* __restrict__ xh1,
                                                    const unsigned short* __restrict__ xh2,
                                                    const unsigned short* __restrict__ xh3,
                                                    const float* __restrict__ Tu,
                                                    const float* __restrict__ projB,
                                                    const int* __restrict__ users,
                                                    const int* __restrict__ items,
                                                    float* __restrict__ out) {
    int lane = threadIdx.x & 63;
    int wid = threadIdx.x >> 6;
    int b = blockIdx.x * 4 + wid;
    if (b >= BATCH) return;
    int u = users[b];
    int it = NUSERS + items[b];
    long long uo = (long long)u * KDIM + lane;
    long long io = (long long)it * KDIM + lane;
    float gu = b2f(xh0[uo]) + b2f(xh1[uo]) + b2f(xh2[uo]) + b2f(xh3[uo]);
    float gi = b2f(xh0[io]) + b2f(xh1[io]) + b2f(xh2[io]) + b2f(xh3[io]);
    float tu = Tu[(long long)u * KDIM + lane];
    float pi = projB[(long long)b * KDIM + lane];
    float v = gu * gi * (1.0f / 16.0f) + tu * pi;
#pragma unroll
    for (int off = 32; off > 0; off >>= 1) v += __shfl_xor(v, off);
    if (lane == 0) out[b] = v;
}

extern "C" void kernel_launch(void* const* d_in, const int* in_sizes, int n_in,
                              void* d_out, int out_size, void* d_ws, size_t ws_size,
                              hipStream_t stream) {
    const float* Gu = (const float*)d_in[0];
    const float* Gi = (const float*)d_in[1];
    const float* Tu = (const float*)d_in[2];
    const float* F = (const float*)d_in[3];
    const float* pw = (const float*)d_in[4];
    const float* pb = (const float*)d_in[5];
    const float* W1 = (const float*)d_in[6];
    const float* b1 = (const float*)d_in[7];
    const float* W2 = (const float*)d_in[8];
    const float* b2 = (const float*)d_in[9];
    const float* ew = (const float*)d_in[10];
    const int* ei = (const int*)d_in[11];
    const int* users = (const int*)d_in[12];
    const int* items = (const int*)d_in[13];
    float* out = (float*)d_out;

    float* projB = (float*)d_ws;                            // BATCH*KDIM f32
    int2* bucket = (int2*)(projB + (size_t)BATCH * KDIM);   // NN*BSLOT int2
    int* cnt = (int*)(bucket + (size_t)NN * BSLOT);         // CNT_PAD int
    unsigned short* aggh = (unsigned short*)(cnt + CNT_PAD);  // NNK bf16
    unsigned short* pwh = aggh + (size_t)NNK;                 // KDIM*FEAT bf16
    unsigned short* xh0 = pwh + (size_t)KDIM * FEAT;          // NNK bf16 x4
    unsigned short* xh1 = xh0 + (size_t)NNK;
    unsigned short* xh2 = xh1 + (size_t)NNK;
    unsigned short* xh3 = xh2 + (size_t)NNK;

    setup_kernel<<<XBLK + CBLK + TBLK, 256, 0, stream>>>(Gu, Gi, pw, xh0, cnt, pwh);
    fill_fixed_kernel<<<(NEDGES + 255) / 256, 256, 0, stream>>>(ei, ew, cnt, bucket);

    // layer 0 aggregation overlapped with the (independent) projection GEMM
    proj_agg0_kernel<<<PROJ_BLOCKS + AGG_BLOCKS, 512, 0, stream>>>(F, pwh, pb, items, projB,
                                                                   xh0, bucket, cnt, aggh);
    gemm_layer_kernel<<<(NN + 63) / 64, 256, 0, stream>>>(xh0, aggh, W1, b1, W2, b2, xh1, 0);

    unsigned short* xs[4] = {xh0, xh1, xh2, xh3};
    for (int ll = 1; ll < NLAYERS; ++ll) {
        agg_kernel<<<(NN + 31) / 32, 256, 0, stream>>>(xs[ll], bucket, cnt, aggh);
        gemm_layer_kernel<<<(NN + 63) / 64, 256, 0, stream>>>(xs[ll], aggh, W1, b1, W2, b2,
                                                              xs[ll + 1], ll);
    }

    final_kernel<<<BATCH / 4, 256, 0, stream>>>(xh0, xh1, xh2, xh3, Tu, projB, users, items, out);
}

// Round 11
// 329.630 us; speedup vs baseline: 1.1445x; 1.0267x over previous
//
#include <hip/hip_runtime.h>

#define NUSERS 50000
#define NITEMS 50000
#define NN (NUSERS + NITEMS)
#define KDIM 64
#define NLAYERS 3
#define FEAT 2048
#define NEDGES 2000000
#define BATCH 8192
#define SLOPE 0.2f

#define BSLOT 64            // fixed bucket capacity per node (max degree ~45 for Poisson(20))
#define CNT_PAD 100352      // 98*1024, int4-zeroable cover of NN
#define XBLK 6250           // NN*KDIM/4 / 256
#define CBLK 98             // CNT_PAD/4/256
#define TBLK 128            // KDIM*FEAT/4/256
#define NNK (NN * KDIM)
#define PROJ_BLOCKS (BATCH / 16)              // 512
#define FILL_BLOCKS ((NEDGES + 511) / 512)    // 3907

typedef __attribute__((ext_vector_type(8))) short bf16x8;
typedef __attribute__((ext_vector_type(4))) float f32x4;

union U8 {
    bf16x8 v;
    uint4 u;
};

// round-to-nearest-even f32 -> bf16
__device__ __forceinline__ unsigned short f2bf(float f) {
    unsigned int u = __float_as_uint(f);
    unsigned int r = (u + 0x7fffu + ((u >> 16) & 1u)) >> 16;
    return (unsigned short)r;
}
__device__ __forceinline__ unsigned int pack2(float a, float b) {
    return (unsigned int)f2bf(a) | ((unsigned int)f2bf(b) << 16);
}
__device__ __forceinline__ float b2f(unsigned short h) {
    return __uint_as_float((unsigned int)h << 16);
}

// ---------------- setup: xh0 = bf16(concat(Gu,Gi)); cnt zero; pwh = bf16(proj_w) ----------------
__global__ __launch_bounds__(256) void setup_kernel(const float* __restrict__ Gu,
                                                    const float* __restrict__ Gi,
                                                    const float* __restrict__ pw,
                                                    unsigned short* __restrict__ xh,
                                                    int* __restrict__ cnt,
                                                    unsigned short* __restrict__ pwh) {
    int bx = blockIdx.x;
    if (bx < XBLK) {
        int i = bx * 256 + threadIdx.x;  // float4 index over NN*KDIM/4
        const int totalU = NUSERS * KDIM / 4;
        float4 v = (i < totalU) ? ((const float4*)Gu)[i] : ((const float4*)Gi)[i - totalU];
        ushort4 h;
        h.x = f2bf(v.x); h.y = f2bf(v.y); h.z = f2bf(v.z); h.w = f2bf(v.w);
        ((ushort4*)xh)[i] = h;
    } else if (bx < XBLK + CBLK) {
        int i = (bx - XBLK) * 256 + threadIdx.x;
        ((int4*)cnt)[i] = make_int4(0, 0, 0, 0);
    } else {
        int i = (bx - XBLK - CBLK) * 256 + threadIdx.x;  // float4 index over KDIM*FEAT/4
        float4 v = ((const float4*)pw)[i];
        ushort4 h;
        h.x = f2bf(v.x); h.y = f2bf(v.y); h.z = f2bf(v.z); h.w = f2bf(v.w);
        ((ushort4*)pwh)[i] = h;
    }
}

// ---------------- merged: proj (blocks [0,512)) + bucket fill (rest), 512 thr ----------------
// Both depend only on setup; fill is atomic/scatter-bound, proj is HBM-stream-bound.
// Bucket entry packed 4B: (src << 15) | (bf16(w) & 0x7FFF)   [w > 0 so sign bit is 0]
__global__ __launch_bounds__(512) void proj_fill_kernel(const float* __restrict__ F,
                                                        const unsigned short* __restrict__ pwh,
                                                        const float* __restrict__ pb,
                                                        const int* __restrict__ items,
                                                        float* __restrict__ projB,
                                                        const int* __restrict__ ei,
                                                        const float* __restrict__ ew,
                                                        int* __restrict__ cnt,
                                                        unsigned int* __restrict__ bucket) {
    __shared__ float lds[8][64][16];
    int t = threadIdx.x;
    if (blockIdx.x >= PROJ_BLOCKS) {
        int e = (blockIdx.x - PROJ_BLOCKS) * 512 + t;
        if (e < NEDGES) {
            int src = ei[e];
            int dst = ei[NEDGES + e];
            int slot = atomicAdd(&cnt[dst], 1);
            if (slot < BSLOT)
                bucket[((long long)dst << 6) + slot] =
                    ((unsigned int)src << 15) | ((unsigned int)f2bf(ew[e]) & 0x7FFFu);
        }
        return;
    }
    // ---- projection via MFMA, split-K over 8 waves ----
    int l = t & 63, w = t >> 6, m16 = l & 15, g4 = l >> 4;
    int i0 = blockIdx.x * 16;
    int item = items[i0 + m16];
    const float* frow = F + (long long)item * FEAT + g4 * 8;
    f32x4 acc[4];
#pragma unroll
    for (int c = 0; c < 4; ++c) acc[c] = (f32x4){0.f, 0.f, 0.f, 0.f};
    float4 fa[8], fb[8];
#pragma unroll
    for (int u = 0; u < 8; ++u) {
        const float* p = frow + (w * 8 + u) * 32;
        fa[u] = *(const float4*)p;
        fb[u] = *(const float4*)(p + 4);
    }
#pragma unroll
    for (int u = 0; u < 8; ++u) {
        U8 af;
        af.u = make_uint4(pack2(fa[u].x, fa[u].y), pack2(fa[u].z, fa[u].w),
                          pack2(fb[u].x, fb[u].y), pack2(fb[u].z, fb[u].w));
#pragma unroll
        for (int c = 0; c < 4; ++c) {
            bf16x8 bw = *(const bf16x8*)(pwh + (long long)(c * 16 + m16) * FEAT +
                                         (w * 8 + u) * 32 + g4 * 8);
            acc[c] = __builtin_amdgcn_mfma_f32_16x16x32_bf16(af.v, bw, acc[c], 0, 0, 0);
        }
    }
#pragma unroll
    for (int c = 0; c < 4; ++c)
#pragma unroll
        for (int reg = 0; reg < 4; ++reg) lds[w][l][c * 4 + reg] = acc[c][reg];
    __syncthreads();
    for (int e = t; e < 1024; e += 512) {
        int ll = e >> 4, v = e & 15;
        float s = lds[0][ll][v];
#pragma unroll
        for (int ww = 1; ww < 8; ++ww) s += lds[ww][ll][v];
        lds[0][ll][v] = s;
    }
    __syncthreads();
    if (w == 0) {
        float av[4][4];
        float sq[4] = {0.f, 0.f, 0.f, 0.f};
#pragma unroll
        for (int c = 0; c < 4; ++c) {
            float bb = pb[c * 16 + m16];
#pragma unroll
            for (int reg = 0; reg < 4; ++reg) {
                float h = lds[0][l][c * 4 + reg] + bb;
                av[c][reg] = h;
                sq[reg] += h * h;
            }
        }
#pragma unroll
        for (int reg = 0; reg < 4; ++reg) {
#pragma unroll
            for (int off = 1; off < 16; off <<= 1) sq[reg] += __shfl_xor(sq[reg], off);
            sq[reg] = 1.0f / fmaxf(sqrtf(sq[reg]), 1e-12f);
        }
#pragma unroll
        for (int reg = 0; reg < 4; ++reg) {
            int b = i0 + g4 * 4 + reg;
#pragma unroll
            for (int c = 0; c < 4; ++c)
                projB[(long long)b * KDIM + c * 16 + m16] = av[c][reg] * sq[reg];
        }
    }
}

// ---------------- aggregate: aggh[n] = bf16( sum_edges w_e * xh[src_e] ) ----------------
// 8 lanes per node, 8 nodes per wave, edge loop unrolled x4; 4B packed bucket entries
__global__ __launch_bounds__(256) void agg_kernel(const unsigned short* __restrict__ xh,
                                                  const unsigned int* __restrict__ bucket,
                                                  const int* __restrict__ cnt,
                                                  unsigned short* __restrict__ aggh) {
    int t = threadIdx.x;
    int lane = t & 63, wid = t >> 6;
    int g = lane >> 3, l8 = lane & 7;
    int n = (blockIdx.x * 4 + wid) * 8 + g;
    if (n >= NN) return;
    int m = cnt[n];
    if (m > BSLOT) m = BSLOT;
    const unsigned int* bk = bucket + ((long long)n << 6);
    const uint4* x4 = (const uint4*)xh;  // row stride 8 uint4
    float a0[8], a1[8], a2[8], a3[8];
#pragma unroll
    for (int q = 0; q < 8; ++q) { a0[q] = 0.f; a1[q] = 0.f; a2[q] = 0.f; a3[q] = 0.f; }
    int j = 0;
    for (; j + 4 <= m; j += 4) {
        unsigned int p0 = bk[j], p1 = bk[j + 1], p2 = bk[j + 2], p3 = bk[j + 3];
        uint4 u0 = x4[((long long)(p0 >> 15) << 3) + l8];
        uint4 u1 = x4[((long long)(p1 >> 15) << 3) + l8];
        uint4 u2 = x4[((long long)(p2 >> 15) << 3) + l8];
        uint4 u3 = x4[((long long)(p3 >> 15) << 3) + l8];
        float w0 = __uint_as_float((p0 & 0x7FFFu) << 16);
        float w1 = __uint_as_float((p1 & 0x7FFFu) << 16);
        float w2 = __uint_as_float((p2 & 0x7FFFu) << 16);
        float w3 = __uint_as_float((p3 & 0x7FFFu) << 16);
        a0[0] += w0 * __uint_as_float(u0.x << 16); a0[1] += w0 * __uint_as_float(u0.x & 0xFFFF0000u);
        a0[2] += w0 * __uint_as_float(u0.y << 16); a0[3] += w0 * __uint_as_float(u0.y & 0xFFFF0000u);
        a0[4] += w0 * __uint_as_float(u0.z << 16); a0[5] += w0 * __uint_as_float(u0.z & 0xFFFF0000u);
        a0[6] += w0 * __uint_as_float(u0.w << 16); a0[7] += w0 * __uint_as_float(u0.w & 0xFFFF0000u);
        a1[0] += w1 * __uint_as_float(u1.x << 16); a1[1] += w1 * __uint_as_float(u1.x & 0xFFFF0000u);
        a1[2] += w1 * __uint_as_float(u1.y << 16); a1[3] += w1 * __uint_as_float(u1.y & 0xFFFF0000u);
        a1[4] += w1 * __uint_as_float(u1.z << 16); a1[5] += w1 * __uint_as_float(u1.z & 0xFFFF0000u);
        a1[6] += w1 * __uint_as_float(u1.w << 16); a1[7] += w1 * __uint_as_float(u1.w & 0xFFFF0000u);
        a2[0] += w2 * __uint_as_float(u2.x << 16); a2[1] += w2 * __uint_as_float(u2.x & 0xFFFF0000u);
        a2[2] += w2 * __uint_as_float(u2.y << 16); a2[3] += w2 * __uint_as_float(u2.y & 0xFFFF0000u);
        a2[4] += w2 * __uint_as_float(u2.z << 16); a2[5] += w2 * __uint_as_float(u2.z & 0xFFFF0000u);
        a2[6] += w2 * __uint_as_float(u2.w << 16); a2[7] += w2 * __uint_as_float(u2.w & 0xFFFF0000u);
        a3[0] += w3 * __uint_as_float(u3.x << 16); a3[1] += w3 * __uint_as_float(u3.x & 0xFFFF0000u);
        a3[2] += w3 * __uint_as_float(u3.y << 16); a3[3] += w3 * __uint_as_float(u3.y & 0xFFFF0000u);
        a3[4] += w3 * __uint_as_float(u3.z << 16); a3[5] += w3 * __uint_as_float(u3.z & 0xFFFF0000u);
        a3[6] += w3 * __uint_as_float(u3.w << 16); a3[7] += w3 * __uint_as_float(u3.w & 0xFFFF0000u);
    }
    for (; j < m; ++j) {
        unsigned int p0 = bk[j];
        uint4 u0 = x4[((long long)(p0 >> 15) << 3) + l8];
        float w0 = __uint_as_float((p0 & 0x7FFFu) << 16);
        a0[0] += w0 * __uint_as_float(u0.x << 16); a0[1] += w0 * __uint_as_float(u0.x & 0xFFFF0000u);
        a0[2] += w0 * __uint_as_float(u0.y << 16); a0[3] += w0 * __uint_as_float(u0.y & 0xFFFF0000u);
        a0[4] += w0 * __uint_as_float(u0.z << 16); a0[5] += w0 * __uint_as_float(u0.z & 0xFFFF0000u);
        a0[6] += w0 * __uint_as_float(u0.w << 16); a0[7] += w0 * __uint_as_float(u0.w & 0xFFFF0000u);
    }
#pragma unroll
    for (int q = 0; q < 8; ++q) a0[q] = (a0[q] + a1[q]) + (a2[q] + a3[q]);
    uint4 o;
    o.x = pack2(a0[0], a0[1]); o.y = pack2(a0[2], a0[3]);
    o.z = pack2(a0[4], a0[5]); o.w = pack2(a0[6], a0[7]);
    *(uint4*)(aggh + (long long)n * KDIM + l8 * 8) = o;
}

// ---------------- NGCF layer via MFMA: xh_out = bf16(l2norm(leaky(S W1^T + b1 + P W2^T + b2))) ----------------
__global__ __launch_bounds__(256) void gemm_layer_kernel(const unsigned short* __restrict__ xh_in,
                                                         const unsigned short* __restrict__ aggh,
                                                         const float* __restrict__ W1,
                                                         const float* __restrict__ b1,
                                                         const float* __restrict__ W2,
                                                         const float* __restrict__ b2,
                                                         unsigned short* __restrict__ xhout,
                                                         int layer) {
    __shared__ unsigned short sS[64 * 72];
    __shared__ unsigned short sP[64 * 72];
    __shared__ unsigned short sW1[64 * 72];
    __shared__ unsigned short sW2[64 * 72];
    int t = threadIdx.x;
    const float* W1g = W1 + (long long)layer * KDIM * KDIM;
    const float* W2g = W2 + (long long)layer * KDIM * KDIM;
    for (int idx = t; idx < KDIM * KDIM; idx += 256) {
        int j = idx >> 6, k = idx & 63;
        sW1[j * 72 + k] = f2bf(W1g[idx]);
        sW2[j * 72 + k] = f2bf(W2g[idx]);
    }
    int n0 = blockIdx.x * 64;
    {
        int r = t >> 2, q = t & 3;
        int node = n0 + r;
        unsigned short* dS = &sS[r * 72 + q * 16];
        unsigned short* dP = &sP[r * 72 + q * 16];
        if (node < NN) {
            const unsigned short* xb = xh_in + (long long)node * KDIM + q * 16;
            const unsigned short* ab = aggh + (long long)node * KDIM + q * 16;
            uint4 hx = *(const uint4*)xb;
            uint4 hx2 = *(const uint4*)(xb + 8);
            uint4 ha = *(const uint4*)ab;
            uint4 ha2 = *(const uint4*)(ab + 8);
            uint4 swv, pwv, swv2, pwv2;
#define PROC(XW, AW, SW, PW)                                                        \
            {                                                                       \
                float xx0 = __uint_as_float((XW) << 16);                            \
                float xx1 = __uint_as_float((XW) & 0xFFFF0000u);                    \
                float aa0 = __uint_as_float((AW) << 16);                            \
                float aa1 = __uint_as_float((AW) & 0xFFFF0000u);                    \
                SW = pack2(xx0 + aa0, xx1 + aa1);                                   \
                PW = pack2(xx0 * aa0, xx1 * aa1);                                   \
            }
            PROC(hx.x, ha.x, swv.x, pwv.x)
            PROC(hx.y, ha.y, swv.y, pwv.y)
            PROC(hx.z, ha.z, swv.z, pwv.z)
            PROC(hx.w, ha.w, swv.w, pwv.w)
            PROC(hx2.x, ha2.x, swv2.x, pwv2.x)
            PROC(hx2.y, ha2.y, swv2.y, pwv2.y)
            PROC(hx2.z, ha2.z, swv2.z, pwv2.z)
            PROC(hx2.w, ha2.w, swv2.w, pwv2.w)
#undef PROC
            *(uint4*)dS = swv;
            *(uint4*)(dS + 8) = swv2;
            *(uint4*)dP = pwv;
            *(uint4*)(dP + 8) = pwv2;
        } else {
            uint4 z = make_uint4(0, 0, 0, 0);
            *(uint4*)dS = z; *(uint4*)(dS + 8) = z;
            *(uint4*)dP = z; *(uint4*)(dP + 8) = z;
        }
    }
    __syncthreads();

    int l = t & 63, w = t >> 6, m16 = l & 15, g4 = l >> 4;
    f32x4 acc[4];
#pragma unroll
    for (int c = 0; c < 4; ++c) {
        float bb = b1[layer * KDIM + c * 16 + m16] + b2[layer * KDIM + c * 16 + m16];
        acc[c] = (f32x4){bb, bb, bb, bb};
    }
    const int abase = (w * 16 + m16) * 72;
#pragma unroll
    for (int kh = 0; kh < 2; ++kh) {
        int ko = kh * 32 + g4 * 8;
        bf16x8 aS = *(const bf16x8*)&sS[abase + ko];
        bf16x8 aP = *(const bf16x8*)&sP[abase + ko];
#pragma unroll
        for (int c = 0; c < 4; ++c) {
            bf16x8 bw1 = *(const bf16x8*)&sW1[(c * 16 + m16) * 72 + ko];
            acc[c] = __builtin_amdgcn_mfma_f32_16x16x32_bf16(aS, bw1, acc[c], 0, 0, 0);
            bf16x8 bw2 = *(const bf16x8*)&sW2[(c * 16 + m16) * 72 + ko];
            acc[c] = __builtin_amdgcn_mfma_f32_16x16x32_bf16(aP, bw2, acc[c], 0, 0, 0);
        }
    }

    float sq[4] = {0.f, 0.f, 0.f, 0.f};
#pragma unroll
    for (int c = 0; c < 4; ++c) {
#pragma unroll
        for (int reg = 0; reg < 4; ++reg) {
            float h = acc[c][reg];
            h = h > 0.f ? h : SLOPE * h;
            acc[c][reg] = h;
            sq[reg] += h * h;
        }
    }
#pragma unroll
    for (int reg = 0; reg < 4; ++reg) {
#pragma unroll
        for (int off = 1; off < 16; off <<= 1) sq[reg] += __shfl_xor(sq[reg], off);
        sq[reg] = 1.0f / fmaxf(sqrtf(sq[reg]), 1e-12f);
    }
#pragma unroll
    for (int reg = 0; reg < 4; ++reg) {
        int node = n0 + w * 16 + g4 * 4 + reg;
        if (node < NN) {
#pragma unroll
            for (int c = 0; c < 4; ++c)
                xhout[(long long)node * KDIM + c * 16 + m16] = f2bf(acc[c][reg] * sq[reg]);
        }
    }
}

// ---------------- final: mean over xh0..xh3 rows + dots ----------------
__global__ __launch_bounds__(256) void final_kernel(const unsigned short* __restrict__ xh0,
                                                    const unsigned short* __restrict__ xh1,
                                                    const unsigned short* __restrict__ xh2,
                                                    const unsigned short* __restrict__ xh3,
                                                    const float* __restrict__ Tu,
                                                    const float* __restrict__ projB,
                                                    const int* __restrict__ users,
                                                    const int* __restrict__ items,
                                                    float* __restrict__ out) {
    int lane = threadIdx.x & 63;
    int wid = threadIdx.x >> 6;
    int b = blockIdx.x * 4 + wid;
    if (b >= BATCH) return;
    int u = users[b];
    int it = NUSERS + items[b];
    long long uo = (long long)u * KDIM + lane;
    long long io = (long long)it * KDIM + lane;
    float gu = b2f(xh0[uo]) + b2f(xh1[uo]) + b2f(xh2[uo]) + b2f(xh3[uo]);
    float gi = b2f(xh0[io]) + b2f(xh1[io]) + b2f(xh2[io]) + b2f(xh3[io]);
    float tu = Tu[(long long)u * KDIM + lane];
    float pi = projB[(long long)b * KDIM + lane];
    float v = gu * gi * (1.0f / 16.0f) + tu * pi;
#pragma unroll
    for (int off = 32; off > 0; off >>= 1) v += __shfl_xor(v, off);
    if (lane == 0) out[b] = v;
}

extern "C" void kernel_launch(void* const* d_in, const int* in_sizes, int n_in,
                              void* d_out, int out_size, void* d_ws, size_t ws_size,
                              hipStream_t stream) {
    const float* Gu = (const float*)d_in[0];
    const float* Gi = (const float*)d_in[1];
    const float* Tu = (const float*)d_in[2];
    const float* F = (const float*)d_in[3];
    const float* pw = (const float*)d_in[4];
    const float* pb = (const float*)d_in[5];
    const float* W1 = (const float*)d_in[6];
    const float* b1 = (const float*)d_in[7];
    const float* W2 = (const float*)d_in[8];
    const float* b2 = (const float*)d_in[9];
    const float* ew = (const float*)d_in[10];
    const int* ei = (const int*)d_in[11];
    const int* users = (const int*)d_in[12];
    const int* items = (const int*)d_in[13];
    float* out = (float*)d_out;

    float* projB = (float*)d_ws;                                   // BATCH*KDIM f32
    unsigned int* bucket = (unsigned int*)(projB + (size_t)BATCH * KDIM);  // NN*BSLOT u32
    int* cnt = (int*)(bucket + (size_t)NN * BSLOT);                // CNT_PAD int
    unsigned short* aggh = (unsigned short*)(cnt + CNT_PAD);       // NNK bf16
    unsigned short* pwh = aggh + (size_t)NNK;                      // KDIM*FEAT bf16
    unsigned short* xh0 = pwh + (size_t)KDIM * FEAT;               // NNK bf16 x4
    unsigned short* xh1 = xh0 + (size_t)NNK;
    unsigned short* xh2 = xh1 + (size_t)NNK;
    unsigned short* xh3 = xh2 + (size_t)NNK;

    setup_kernel<<<XBLK + CBLK + TBLK, 256, 0, stream>>>(Gu, Gi, pw, xh0, cnt, pwh);
    // bucket fill overlapped with the (independent) projection GEMM
    proj_fill_kernel<<<PROJ_BLOCKS + FILL_BLOCKS, 512, 0, stream>>>(F, pwh, pb, items, projB,
                                                                    ei, ew, cnt, bucket);

    unsigned short* xs[4] = {xh0, xh1, xh2, xh3};
    for (int ll = 0; ll < NLAYERS; ++ll) {
        agg_kernel<<<(NN + 31) / 32, 256, 0, stream>>>(xs[ll], bucket, cnt, aggh);
        gemm_layer_kernel<<<(NN + 63) / 64, 256, 0, stream>>>(xs[ll], aggh, W1, b1, W2, b2,
                                                              xs[ll + 1], ll);
    }

    final_kernel<<<BATCH / 4, 256, 0, stream>>>(xh0, xh1, xh2, xh3, Tu, projB, users, items, out);
}